// Round 1
// baseline (211.667 us; speedup 1.0000x reference)
//
#include <hip/hip_runtime.h>

// Fold / col2im: x[16, 9, 512, 512] f32 -> out[16, 1, 512, 512] f32
// out[b,p,q] = sum_{i,j in 0..2} x[b, i*3+j, p+1-i, q+1-j]  (OOB taps = 0)
//
// Memory-bound: 151 MB read + 17 MB write, no reuse.
//
// v2: all loads 16B-aligned. Per thread (4 consecutive outputs) accumulate
// aligned column sums A (j=0 channels 0,3,6), B (j=1), C (j=2) over the
// valid rows, then apply the +/-1 column shift in-register:
//     out[t] = A[t+1] + B[t] + C[t-1]
// Cross-thread elements (A at q0+4, C at q0-1) come from one __shfl each;
// lanes 0/63 patch the wave boundary with a predicated scalar load.
// A wave (64 lanes x 4 floats = 256 cols) never spans a row, so p and the
// row-clip branches are wave-uniform.

constexpr int B = 16;
constexpr int C = 9;
constexpr int H = 512;
constexpr int W = 512;
constexpr int WV = W / 4;  // 128 float4 groups per row

typedef float f4 __attribute__((ext_vector_type(4)));  // 16B aligned

__global__ __launch_bounds__(256) void fold_kernel(const float* __restrict__ x,
                                                   float* __restrict__ out) {
    const int tid = blockIdx.x * blockDim.x + threadIdx.x;  // [0, B*H*WV)
    const int qv = tid & (WV - 1);
    const int t2 = tid >> 7;        // / WV
    const int p  = t2 & (H - 1);
    const int b  = t2 >> 9;         // / H
    const int q0 = qv * 4;
    const int lane = threadIdx.x & 63;

    const size_t plane = (size_t)H * W;
    const float* xb = x + (size_t)b * C * plane;

    f4 A  = {0.f, 0.f, 0.f, 0.f};   // sum_i x[3i+0][r_i][q0..q0+3]
    f4 Bv = {0.f, 0.f, 0.f, 0.f};   // sum_i x[3i+1][r_i][q0..q0+3]
    f4 Cv = {0.f, 0.f, 0.f, 0.f};   // sum_i x[3i+2][r_i][q0..q0+3]
    float aR = 0.f, cL = 0.f;

    const bool needR = (lane == 63) && (q0 + 4 < W);  // mid-row wave boundary
    const bool needL = (lane == 0) && (q0 > 0);

#pragma unroll
    for (int i = 0; i < 3; ++i) {
        const int r = p + 1 - i;
        if (r < 0 || r >= H) continue;  // padded row -> zero contribution
        const float* r0 = xb + (size_t)(3 * i + 0) * plane + (size_t)r * W;
        const float* r1 = xb + (size_t)(3 * i + 1) * plane + (size_t)r * W;
        const float* r2 = xb + (size_t)(3 * i + 2) * plane + (size_t)r * W;

        A  += *reinterpret_cast<const f4*>(r0 + q0);
        Bv += *reinterpret_cast<const f4*>(r1 + q0);
        Cv += *reinterpret_cast<const f4*>(r2 + q0);

        if (needR) aR += r0[q0 + 4];   // only lane 63, only mid-row
        if (needL) cL += r2[q0 - 1];   // only lane 0, only mid-row
    }

    // +1 shift for A: out[q0+3] needs A at column q0+4 = lane+1's A.x
    float a_next = __shfl_down(A.x, 1, 64);
    if (lane == 63) a_next = aR;
    // -1 shift for C: out[q0] needs C at column q0-1 = lane-1's C.w
    float c_prev = __shfl_up(Cv.w, 1, 64);
    if (lane == 0) c_prev = cL;

    f4 o;
    o.x = A.y    + Bv.x + c_prev;
    o.y = A.z    + Bv.y + Cv.x;
    o.z = A.w    + Bv.z + Cv.y;
    o.w = a_next + Bv.w + Cv.z;

    // out offset = tid*4 floats, 16B aligned; pure streaming -> nontemporal.
    __builtin_nontemporal_store(o, reinterpret_cast<f4*>(out + (size_t)tid * 4));
}

extern "C" void kernel_launch(void* const* d_in, const int* in_sizes, int n_in,
                              void* d_out, int out_size, void* d_ws, size_t ws_size,
                              hipStream_t stream) {
    const float* x = (const float*)d_in[0];
    float* out = (float*)d_out;
    const int n_threads = B * H * WV;   // 16*512*128 = 1,048,576
    const int block = 256;
    const int grid = n_threads / block; // 4096
    fold_kernel<<<grid, block, 0, stream>>>(x, out);
}

// Round 2
// 206.411 us; speedup vs baseline: 1.0255x; 1.0255x over previous
//
#include <hip/hip_runtime.h>

// Fold / col2im: x[16, 9, 512, 512] f32 -> out[16, 1, 512, 512] f32
// out[b,p,q] = sum_{i,j in 0..2} x[b, i*3+j, p+1-i, q+1-j]  (OOB taps = 0)
//
// Memory-bound: 151 MB read + 17 MB write, each input byte read exactly once.
//
// v3: 8 outputs per thread (one wave = one full 512-col row -> p and the
// row-clip branches are wave-uniform). Per tap: two unaligned float4 loads.
// Column edges handled by masking the single over-read element in-register
// (the +/-1 over-read is provably inside the allocation: left-edge taps are
// channels {2,5,8}, right-edge taps are channels {0,3,6} -> never the buffer
// ends). No divergent scalar path. Nontemporal loads/stores: pure streaming,
// no reuse -> don't pollute L2. Per-element accumulation stays in ch=0..8
// order -> bit-exact vs the JAX reference (absmax 0).

constexpr int B = 16;
constexpr int C = 9;
constexpr int H = 512;
constexpr int W = 512;
constexpr int W8 = W / 8;  // 64 groups of 8 per row; one wave covers one row

// 4-byte-aligned float4: tap loads are shifted by +/-1 element.
typedef float f4_u __attribute__((ext_vector_type(4), aligned(4)));

__global__ __launch_bounds__(256) void fold_kernel(const float* __restrict__ x,
                                                   float* __restrict__ out) {
    const int tid = blockIdx.x * blockDim.x + threadIdx.x;  // [0, B*H*W8)
    const int qv = tid & (W8 - 1);      // == lane
    const int t2 = tid >> 6;
    const int p  = t2 & (H - 1);        // wave-uniform
    const int b  = t2 >> 9;             // wave-uniform
    const int q0 = qv * 8;

    const size_t plane = (size_t)H * W;
    const float* xb = x + (size_t)b * C * plane;

    float a0 = 0.f, a1 = 0.f, a2 = 0.f, a3 = 0.f;
    float a4 = 0.f, a5 = 0.f, a6 = 0.f, a7 = 0.f;

    const bool left_edge  = (qv == 0);
    const bool right_edge = (qv == W8 - 1);

#pragma unroll
    for (int i = 0; i < 3; ++i) {
        const int r = p + 1 - i;
        if (r < 0 || r >= H) continue;  // padded row -> zero; wave-uniform
        const float* xr = xb + (size_t)(3 * i) * plane + (size_t)r * W;
#pragma unroll
        for (int j = 0; j < 3; ++j) {
            const float* xrow = xr + (size_t)j * plane;
            const int c0 = q0 + 1 - j;  // leftmost column of this tap's 8-vec
            f4_u v0 = __builtin_nontemporal_load(
                reinterpret_cast<const f4_u*>(xrow + c0));
            f4_u v1 = __builtin_nontemporal_load(
                reinterpret_cast<const f4_u*>(xrow + c0 + 4));
            // Mask the one over-read element at row edges (in-register, no
            // divergent path; adding 0.0f keeps bit-exactness).
            if (j == 2 && left_edge)  v0.x = 0.f;  // col -1
            if (j == 0 && right_edge) v1.w = 0.f;  // col W
            a0 += v0.x; a1 += v0.y; a2 += v0.z; a3 += v0.w;
            a4 += v1.x; a5 += v1.y; a6 += v1.z; a7 += v1.w;
        }
    }

    // out offset = tid*8 floats (32B aligned); pure streaming store.
    float* o = out + (size_t)tid * 8;
    f4_u r0; r0.x = a0; r0.y = a1; r0.z = a2; r0.w = a3;
    f4_u r1; r1.x = a4; r1.y = a5; r1.z = a6; r1.w = a7;
    __builtin_nontemporal_store(r0, reinterpret_cast<f4_u*>(o));
    __builtin_nontemporal_store(r1, reinterpret_cast<f4_u*>(o + 4));
}

extern "C" void kernel_launch(void* const* d_in, const int* in_sizes, int n_in,
                              void* d_out, int out_size, void* d_ws, size_t ws_size,
                              hipStream_t stream) {
    const float* x = (const float*)d_in[0];
    float* out = (float*)d_out;
    const int n_threads = B * H * W8;   // 16*512*64 = 524,288
    const int block = 256;
    const int grid = n_threads / block; // 2048
    fold_kernel<<<grid, block, 0, stream>>>(x, out);
}